// Round 1
// baseline (546.855 us; speedup 1.0000x reference)
//
#include <hip/hip_runtime.h>

// Problem constants (fixed by setup_inputs)
#define B_   8
#define H_   512
#define W_   1024
#define FH_  128
#define FW_  256
#define TW   32
#define TH   8

__device__ __forceinline__ float wave_reduce(float v) {
    #pragma unroll
    for (int off = 32; off > 0; off >>= 1) v += __shfl_down(v, off, 64);
    return v;
}

// Main fused kernel: per 32x8 tile, build (34x10) halo of img1 and warped img2
// in LDS, then 3x3 SSIM pools + L1 + masked accumulation.
__global__ __launch_bounds__(256)
void fused_main(const float* __restrict__ flow, const float* __restrict__ img1,
                const float* __restrict__ img2, const float* __restrict__ mask,
                float* __restrict__ accum) {
    const int b   = blockIdx.z;
    const int tx0 = blockIdx.x * TW;
    const int ty0 = blockIdx.y * TH;
    const int tid = threadIdx.x;

    __shared__ float s1[3][TH + 2][TW + 4];   // img1 tile (+halo), padded stride
    __shared__ float s2[3][TH + 2][TW + 4];   // warped img2 tile (+halo)

    const size_t plane = (size_t)H_ * W_;
    const float* f0  = flow + (size_t)b * 2 * FH_ * FW_;        // flow x
    const float* f1  = f0 + FH_ * FW_;                          // flow y
    const float* i1b = img1 + (size_t)b * 3 * plane;
    const float* i2b = img2 + (size_t)b * 3 * plane;

    // ---- Stage halo: img1 + warped img2 (zero outside image: pool zero-pad) ----
    for (int i = tid; i < (TH + 2) * (TW + 2); i += 256) {
        const int ly = i / (TW + 2);
        const int lx = i - ly * (TW + 2);
        const int gy = ty0 + ly - 1;
        const int gx = tx0 + lx - 1;
        float v1[3] = {0.f, 0.f, 0.f};
        float v2[3] = {0.f, 0.f, 0.f};
        if (gy >= 0 && gy < H_ && gx >= 0 && gx < W_) {
            const size_t p = (size_t)gy * W_ + gx;
            v1[0] = i1b[p];
            v1[1] = i1b[p + plane];
            v1[2] = i1b[p + 2 * plane];

            // flow upsample, bilinear align_corners: yc = gy*(fh-1)/(H-1)
            const float yc = gy * (127.0f / 511.0f);
            const float xc = gx * (255.0f / 1023.0f);
            const int y0 = (int)yc, x0 = (int)xc;               // coords >= 0
            const int y1 = min(y0 + 1, FH_ - 1);
            const int x1 = min(x0 + 1, FW_ - 1);
            const float wy = yc - y0, wx = xc - x0;
            const int r0 = y0 * FW_, r1 = y1 * FW_;
            const float fx = (f0[r0 + x0] * (1.f - wx) + f0[r0 + x1] * wx) * (1.f - wy)
                           + (f0[r1 + x0] * (1.f - wx) + f0[r1 + x1] * wx) * wy;
            const float fy = (f1[r0 + x0] * (1.f - wx) + f1[r0 + x1] * wx) * (1.f - wy)
                           + (f1[r1 + x0] * (1.f - wx) + f1[r1 + x1] * wx) * wy;

            // grid_sample border, align_corners: sample at (gx + 4*fx, gy + 4*fy)
            const float gxs = fminf(fmaxf((float)gx + 4.0f * fx, 0.0f), (float)(W_ - 1));
            const float gys = fminf(fmaxf((float)gy + 4.0f * fy, 0.0f), (float)(H_ - 1));
            const int sx0 = (int)gxs, sy0 = (int)gys;
            const int sx1 = min(sx0 + 1, W_ - 1);
            const int sy1 = min(sy0 + 1, H_ - 1);
            const float swx = gxs - sx0, swy = gys - sy0;
            const size_t p00 = (size_t)sy0 * W_ + sx0;
            const size_t p01 = (size_t)sy0 * W_ + sx1;
            const size_t p10 = (size_t)sy1 * W_ + sx0;
            const size_t p11 = (size_t)sy1 * W_ + sx1;
            #pragma unroll
            for (int c = 0; c < 3; ++c) {
                const float* im = i2b + (size_t)c * plane;
                const float top = im[p00] * (1.f - swx) + im[p01] * swx;
                const float bot = im[p10] * (1.f - swx) + im[p11] * swx;
                v2[c] = top * (1.f - swy) + bot * swy;
            }
        }
        #pragma unroll
        for (int c = 0; c < 3; ++c) { s1[c][ly][lx] = v1[c]; s2[c][ly][lx] = v2[c]; }
    }
    __syncthreads();

    // ---- Center pixel: SSIM pools + L1 + mask ----
    const int lx = tid & (TW - 1);
    const int ly = tid >> 5;            // 256 threads -> 32x8
    const int gx = tx0 + lx;
    const int gy = ty0 + ly;

    const float inv9 = 1.0f / 9.0f;
    const float C1 = 0.0001f, C2 = 0.0009f;
    float distSum = 0.f, l1sum = 0.f;
    #pragma unroll
    for (int c = 0; c < 3; ++c) {
        float sx = 0.f, sy = 0.f, sxx = 0.f, syy = 0.f, sxy = 0.f;
        #pragma unroll
        for (int dy = 0; dy < 3; ++dy) {
            #pragma unroll
            for (int dx = 0; dx < 3; ++dx) {
                const float a = s1[c][ly + dy][lx + dx];
                const float b2 = s2[c][ly + dy][lx + dx];
                sx += a; sy += b2;
                sxx = fmaf(a, a, sxx);
                syy = fmaf(b2, b2, syy);
                sxy = fmaf(a, b2, sxy);
            }
        }
        const float mx = sx * inv9, my = sy * inv9;
        const float vx = sxx * inv9 - mx * mx;
        const float vy = syy * inv9 - my * my;
        const float vxy = sxy * inv9 - mx * my;
        const float ssim = (2.f * mx * my + C1) * (2.f * vxy + C2) /
                           ((mx * mx + my * my + C1) * (vx + vy + C2) + 1e-12f);
        distSum += fminf(fmaxf((1.0f - ssim) * 0.5f, 0.f), 1.f);
        l1sum += fabsf(s1[c][ly + 1][lx + 1] - s2[c][ly + 1][lx + 1]);
    }
    const float pm = 0.85f * (distSum * (1.0f / 3.0f)) + 0.15f * (l1sum * (1.0f / 3.0f));
    const float m  = (mask[(size_t)b * plane + (size_t)gy * W_ + gx] > 0.5f) ? 1.f : 0.f;

    float num = wave_reduce(pm * m);
    float den = wave_reduce(m);
    __shared__ float rn[4], rd[4];
    const int wid = tid >> 6, lane = tid & 63;
    if (lane == 0) { rn[wid] = num; rd[wid] = den; }
    __syncthreads();
    if (tid == 0) {
        atomicAdd(&accum[0], rn[0] + rn[1] + rn[2] + rn[3]);
        atomicAdd(&accum[1], rd[0] + rd[1] + rd[2] + rd[3]);
    }
}

// Smoothness loss on raw flow: sum |dx| and |dy| separately (different counts).
__global__ __launch_bounds__(256)
void smooth_kernel(const float* __restrict__ flow, float* __restrict__ accum) {
    const int N = B_ * 2 * FH_ * FW_;
    float dxs = 0.f, dys = 0.f;
    for (int i = blockIdx.x * 256 + threadIdx.x; i < N; i += gridDim.x * 256) {
        const float f = flow[i];
        const int x = i & (FW_ - 1);
        const int y = (i >> 8) & (FH_ - 1);
        if (x < FW_ - 1) dxs += fabsf(f - flow[i + 1]);
        if (y < FH_ - 1) dys += fabsf(f - flow[i + FW_]);
    }
    dxs = wave_reduce(dxs);
    dys = wave_reduce(dys);
    __shared__ float rn[4], rd[4];
    const int wid = threadIdx.x >> 6, lane = threadIdx.x & 63;
    if (lane == 0) { rn[wid] = dxs; rd[wid] = dys; }
    __syncthreads();
    if (threadIdx.x == 0) {
        atomicAdd(&accum[2], rn[0] + rn[1] + rn[2] + rn[3]);
        atomicAdd(&accum[3], rd[0] + rd[1] + rd[2] + rd[3]);
    }
}

__global__ void finalize_kernel(const float* __restrict__ accum, float* __restrict__ out) {
    const float photo  = accum[0] / fmaxf(accum[1], 1.0f);
    const float mean_dx = accum[2] / (float)(B_ * 2 * FH_ * (FW_ - 1));
    const float mean_dy = accum[3] / (float)(B_ * 2 * (FH_ - 1) * FW_);
    const float smooth = mean_dx + mean_dy;
    out[0] = photo + 0.1f * smooth;   // total
    out[1] = photo;
    out[2] = smooth;
}

extern "C" void kernel_launch(void* const* d_in, const int* in_sizes, int n_in,
                              void* d_out, int out_size, void* d_ws, size_t ws_size,
                              hipStream_t stream) {
    const float* flow = (const float*)d_in[0];
    const float* img1 = (const float*)d_in[1];
    const float* img2 = (const float*)d_in[2];
    const float* mask = (const float*)d_in[3];
    float* out   = (float*)d_out;
    float* accum = (float*)d_ws;   // [num, den, dx_sum, dy_sum]

    hipMemsetAsync(accum, 0, 4 * sizeof(float), stream);
    smooth_kernel<<<256, 256, 0, stream>>>(flow, accum);
    dim3 grid(W_ / TW, H_ / TH, B_);
    fused_main<<<grid, 256, 0, stream>>>(flow, img1, img2, mask, accum);
    finalize_kernel<<<1, 1, 0, stream>>>(accum, out);
}

// Round 3
// 214.592 us; speedup vs baseline: 2.5483x; 2.5483x over previous
//
#include <hip/hip_runtime.h>

// Problem constants (fixed by setup_inputs)
#define B_   8
#define H_   512
#define W_   1024
#define FH_  128
#define FW_  256
#define TW   32
#define TH   8
#define NSLOT 256   // spread accumulator slots (16B each = one bank-spread line set)

__device__ __forceinline__ float wave_reduce(float v) {
    #pragma unroll
    for (int off = 32; off > 0; off >>= 1) v += __shfl_down(v, off, 64);
    return v;
}

// Main fused kernel: per 32x8 tile, build (34x10) halo of img1 and warped img2
// in LDS, then 3x3 SSIM pools + L1 + masked accumulation.
// Atomics go to slot (linear_bid & 255) -> 64 blocks/address, no serialization.
__global__ __launch_bounds__(256)
void fused_main(const float* __restrict__ flow, const float* __restrict__ img1,
                const float* __restrict__ img2, const float* __restrict__ mask,
                float* __restrict__ accum) {
    const int b   = blockIdx.z;
    const int tx0 = blockIdx.x * TW;
    const int ty0 = blockIdx.y * TH;
    const int tid = threadIdx.x;

    __shared__ float s1[3][TH + 2][TW + 4];   // img1 tile (+halo), padded stride
    __shared__ float s2[3][TH + 2][TW + 4];   // warped img2 tile (+halo)

    const size_t plane = (size_t)H_ * W_;
    const float* f0  = flow + (size_t)b * 2 * FH_ * FW_;        // flow x
    const float* f1  = f0 + FH_ * FW_;                          // flow y
    const float* i1b = img1 + (size_t)b * 3 * plane;
    const float* i2b = img2 + (size_t)b * 3 * plane;

    // ---- Stage halo: img1 + warped img2 (zero outside image: pool zero-pad) ----
    for (int i = tid; i < (TH + 2) * (TW + 2); i += 256) {
        const int ly = i / (TW + 2);
        const int lx = i - ly * (TW + 2);
        const int gy = ty0 + ly - 1;
        const int gx = tx0 + lx - 1;
        float v1[3] = {0.f, 0.f, 0.f};
        float v2[3] = {0.f, 0.f, 0.f};
        if (gy >= 0 && gy < H_ && gx >= 0 && gx < W_) {
            const size_t p = (size_t)gy * W_ + gx;
            v1[0] = i1b[p];
            v1[1] = i1b[p + plane];
            v1[2] = i1b[p + 2 * plane];

            // flow upsample, bilinear align_corners: yc = gy*(fh-1)/(H-1)
            const float yc = gy * (127.0f / 511.0f);
            const float xc = gx * (255.0f / 1023.0f);
            const int y0 = (int)yc, x0 = (int)xc;               // coords >= 0
            const int y1 = min(y0 + 1, FH_ - 1);
            const int x1 = min(x0 + 1, FW_ - 1);
            const float wy = yc - y0, wx = xc - x0;
            const int r0 = y0 * FW_, r1 = y1 * FW_;
            const float fx = (f0[r0 + x0] * (1.f - wx) + f0[r0 + x1] * wx) * (1.f - wy)
                           + (f0[r1 + x0] * (1.f - wx) + f0[r1 + x1] * wx) * wy;
            const float fy = (f1[r0 + x0] * (1.f - wx) + f1[r0 + x1] * wx) * (1.f - wy)
                           + (f1[r1 + x0] * (1.f - wx) + f1[r1 + x1] * wx) * wy;

            // grid_sample border, align_corners: sample at (gx + 4*fx, gy + 4*fy)
            const float gxs = fminf(fmaxf((float)gx + 4.0f * fx, 0.0f), (float)(W_ - 1));
            const float gys = fminf(fmaxf((float)gy + 4.0f * fy, 0.0f), (float)(H_ - 1));
            const int sx0 = (int)gxs, sy0 = (int)gys;
            const int sx1 = min(sx0 + 1, W_ - 1);
            const int sy1 = min(sy0 + 1, H_ - 1);
            const float swx = gxs - sx0, swy = gys - sy0;
            const size_t p00 = (size_t)sy0 * W_ + sx0;
            const size_t p01 = (size_t)sy0 * W_ + sx1;
            const size_t p10 = (size_t)sy1 * W_ + sx0;
            const size_t p11 = (size_t)sy1 * W_ + sx1;
            #pragma unroll
            for (int c = 0; c < 3; ++c) {
                const float* im = i2b + (size_t)c * plane;
                const float top = im[p00] * (1.f - swx) + im[p01] * swx;
                const float bot = im[p10] * (1.f - swx) + im[p11] * swx;
                v2[c] = top * (1.f - swy) + bot * swy;
            }
        }
        #pragma unroll
        for (int c = 0; c < 3; ++c) { s1[c][ly][lx] = v1[c]; s2[c][ly][lx] = v2[c]; }
    }
    __syncthreads();

    // ---- Center pixel: SSIM pools + L1 + mask ----
    const int lx = tid & (TW - 1);
    const int ly = tid >> 5;            // 256 threads -> 32x8
    const int gx = tx0 + lx;
    const int gy = ty0 + ly;

    const float inv9 = 1.0f / 9.0f;
    const float C1 = 0.0001f, C2 = 0.0009f;
    float distSum = 0.f, l1sum = 0.f;
    #pragma unroll
    for (int c = 0; c < 3; ++c) {
        float sx = 0.f, sy = 0.f, sxx = 0.f, syy = 0.f, sxy = 0.f;
        #pragma unroll
        for (int dy = 0; dy < 3; ++dy) {
            #pragma unroll
            for (int dx = 0; dx < 3; ++dx) {
                const float a = s1[c][ly + dy][lx + dx];
                const float b2 = s2[c][ly + dy][lx + dx];
                sx += a; sy += b2;
                sxx = fmaf(a, a, sxx);
                syy = fmaf(b2, b2, syy);
                sxy = fmaf(a, b2, sxy);
            }
        }
        const float mx = sx * inv9, my = sy * inv9;
        const float vx = sxx * inv9 - mx * mx;
        const float vy = syy * inv9 - my * my;
        const float vxy = sxy * inv9 - mx * my;
        const float ssim = (2.f * mx * my + C1) * (2.f * vxy + C2) /
                           ((mx * mx + my * my + C1) * (vx + vy + C2) + 1e-12f);
        distSum += fminf(fmaxf((1.0f - ssim) * 0.5f, 0.f), 1.f);
        l1sum += fabsf(s1[c][ly + 1][lx + 1] - s2[c][ly + 1][lx + 1]);
    }
    const float pm = 0.85f * (distSum * (1.0f / 3.0f)) + 0.15f * (l1sum * (1.0f / 3.0f));
    const float m  = (mask[(size_t)b * plane + (size_t)gy * W_ + gx] > 0.5f) ? 1.f : 0.f;

    float num = wave_reduce(pm * m);
    float den = wave_reduce(m);
    __shared__ float rn[4], rd[4];
    const int wid = tid >> 6, lane = tid & 63;
    if (lane == 0) { rn[wid] = num; rd[wid] = den; }
    __syncthreads();
    if (tid == 0) {
        const int lin  = (blockIdx.z * gridDim.y + blockIdx.y) * gridDim.x + blockIdx.x;
        float* slot = accum + (size_t)(lin & (NSLOT - 1)) * 4;
        atomicAdd(&slot[0], rn[0] + rn[1] + rn[2] + rn[3]);
        atomicAdd(&slot[1], rd[0] + rd[1] + rd[2] + rd[3]);
    }
}

// Smoothness loss on raw flow: sum |dx| and |dy| separately (different counts).
// One block per slot -> zero atomic contention.
__global__ __launch_bounds__(256)
void smooth_kernel(const float* __restrict__ flow, float* __restrict__ accum) {
    const int N = B_ * 2 * FH_ * FW_;
    float dxs = 0.f, dys = 0.f;
    for (int i = blockIdx.x * 256 + threadIdx.x; i < N; i += gridDim.x * 256) {
        const float f = flow[i];
        const int x = i & (FW_ - 1);
        const int y = (i >> 8) & (FH_ - 1);
        if (x < FW_ - 1) dxs += fabsf(f - flow[i + 1]);
        if (y < FH_ - 1) dys += fabsf(f - flow[i + FW_]);
    }
    dxs = wave_reduce(dxs);
    dys = wave_reduce(dys);
    __shared__ float rn[4], rd[4];
    const int wid = threadIdx.x >> 6, lane = threadIdx.x & 63;
    if (lane == 0) { rn[wid] = dxs; rd[wid] = dys; }
    __syncthreads();
    if (threadIdx.x == 0) {
        float* slot = accum + (size_t)blockIdx.x * 4;
        atomicAdd(&slot[2], rn[0] + rn[1] + rn[2] + rn[3]);
        atomicAdd(&slot[3], rd[0] + rd[1] + rd[2] + rd[3]);
    }
}

// Reduce the 256 accumulator slots and emit the 3 outputs.
__global__ __launch_bounds__(256)
void finalize_kernel(const float* __restrict__ accum, float* __restrict__ out) {
    const int t = threadIdx.x;
    float num = accum[t * 4 + 0];
    float den = accum[t * 4 + 1];
    float dxs = accum[t * 4 + 2];
    float dys = accum[t * 4 + 3];
    num = wave_reduce(num); den = wave_reduce(den);
    dxs = wave_reduce(dxs); dys = wave_reduce(dys);
    __shared__ float r[4][4];
    const int wid = t >> 6, lane = t & 63;
    if (lane == 0) { r[wid][0] = num; r[wid][1] = den; r[wid][2] = dxs; r[wid][3] = dys; }
    __syncthreads();
    if (t == 0) {
        const float tn = r[0][0] + r[1][0] + r[2][0] + r[3][0];
        const float td = r[0][1] + r[1][1] + r[2][1] + r[3][1];
        const float tx = r[0][2] + r[1][2] + r[2][2] + r[3][2];
        const float ty = r[0][3] + r[1][3] + r[2][3] + r[3][3];
        const float photo   = tn / fmaxf(td, 1.0f);
        const float mean_dx = tx / (float)(B_ * 2 * FH_ * (FW_ - 1));
        const float mean_dy = ty / (float)(B_ * 2 * (FH_ - 1) * FW_);
        const float smooth  = mean_dx + mean_dy;
        out[0] = photo + 0.1f * smooth;   // total
        out[1] = photo;
        out[2] = smooth;
    }
}

extern "C" void kernel_launch(void* const* d_in, const int* in_sizes, int n_in,
                              void* d_out, int out_size, void* d_ws, size_t ws_size,
                              hipStream_t stream) {
    const float* flow = (const float*)d_in[0];
    const float* img1 = (const float*)d_in[1];
    const float* img2 = (const float*)d_in[2];
    const float* mask = (const float*)d_in[3];
    float* out   = (float*)d_out;
    float* accum = (float*)d_ws;   // NSLOT x [num, den, dx_sum, dy_sum]

    hipMemsetAsync(accum, 0, NSLOT * 4 * sizeof(float), stream);
    smooth_kernel<<<NSLOT, 256, 0, stream>>>(flow, accum);
    dim3 grid(W_ / TW, H_ / TH, B_);
    fused_main<<<grid, 256, 0, stream>>>(flow, img1, img2, mask, accum);
    finalize_kernel<<<1, 256, 0, stream>>>(accum, out);
}

// Round 4
// 204.714 us; speedup vs baseline: 2.6713x; 1.0483x over previous
//
#include <hip/hip_runtime.h>

// Problem constants (fixed by setup_inputs)
#define B_   8
#define H_   512
#define W_   1024
#define FH_  128
#define FW_  256
#define TW   64
#define TH   16
#define HW_  (TW + 2)    // 66
#define HH_  (TH + 2)    // 18
#define NSLOT 256

__device__ __forceinline__ float wave_reduce(float v) {
    #pragma unroll
    for (int off = 32; off > 0; off >>= 1) v += __shfl_down(v, off, 64);
    return v;
}

// Horizontal 3-col sums of the 5 SSIM quantities at one LDS row.
__device__ __forceinline__ void hrow(const float* __restrict__ a, const float* __restrict__ b,
                                     float& hA, float& hB, float& hAA, float& hBB, float& hAB) {
    const float a0 = a[0], a1 = a[1], a2 = a[2];
    const float b0 = b[0], b1 = b[1], b2 = b[2];
    hA  = a0 + a1 + a2;
    hB  = b0 + b1 + b2;
    hAA = fmaf(a0, a0, fmaf(a1, a1, a2 * a2));
    hBB = fmaf(b0, b0, fmaf(b1, b1, b2 * b2));
    hAB = fmaf(a0, b0, fmaf(a1, b1, a2 * b2));
}

// Fused: per 64x16 tile, stage img1 + warped img2 (66x18 halo) in LDS,
// rolling-window 3x3 SSIM (each thread = 1 column x 4 consecutive rows),
// masked accumulation into 256 spread slots.
__global__ __launch_bounds__(256)
void fused_main(const float* __restrict__ flow, const float* __restrict__ img1,
                const float* __restrict__ img2, const float* __restrict__ mask,
                float* __restrict__ accum) {
    const int b   = blockIdx.z;
    const int tx0 = blockIdx.x * TW;
    const int ty0 = blockIdx.y * TH;
    const int tid = threadIdx.x;

    __shared__ float s1[3][HH_][HW_];
    __shared__ float s2[3][HH_][HW_];

    const uint32_t plane = (uint32_t)H_ * W_;
    // Wave-uniform per-channel base pointers -> saddr + 32-bit voffset loads.
    const float* f0  = flow + (size_t)b * 2 * FH_ * FW_;
    const float* f1  = f0 + FH_ * FW_;
    const float* i10 = img1 + (size_t)b * 3 * plane;
    const float* i11 = i10 + plane;
    const float* i12 = i11 + plane;
    const float* i20 = img2 + (size_t)b * 3 * plane;
    const float* i21 = i20 + plane;
    const float* i22 = i21 + plane;

    // ---- Stage halo: img1 + warped img2 (zeros outside image: pool zero-pad) ----
    for (int i = tid; i < HH_ * HW_; i += 256) {
        const int ly = i / HW_;
        const int lx = i - ly * HW_;
        const int gy = ty0 + ly - 1;
        const int gx = tx0 + lx - 1;
        float v10 = 0.f, v11 = 0.f, v12 = 0.f;
        float v20 = 0.f, v21 = 0.f, v22 = 0.f;
        if (gy >= 0 && gy < H_ && gx >= 0 && gx < W_) {
            const uint32_t p = (uint32_t)gy * W_ + (uint32_t)gx;
            v10 = i10[p]; v11 = i11[p]; v12 = i12[p];

            // flow upsample, bilinear align_corners
            const float yc = gy * (127.0f / 511.0f);
            const float xc = gx * (255.0f / 1023.0f);
            const int y0 = (int)yc, x0 = (int)xc;
            const int y1i = min(y0 + 1, FH_ - 1);
            const int x1i = min(x0 + 1, FW_ - 1);
            const float wy = yc - (float)y0, wx = xc - (float)x0;
            const uint32_t r0 = (uint32_t)y0 * FW_;
            const uint32_t r1 = (uint32_t)y1i * FW_;
            const float a00 = f0[r0 + x0], a01 = f0[r0 + x1i];
            const float a10 = f0[r1 + x0], a11 = f0[r1 + x1i];
            const float c00 = f1[r0 + x0], c01 = f1[r0 + x1i];
            const float c10 = f1[r1 + x0], c11 = f1[r1 + x1i];
            const float fxt = a00 + wx * (a01 - a00);
            const float fxb = a10 + wx * (a11 - a10);
            const float fx  = fxt + wy * (fxb - fxt);
            const float fyt = c00 + wx * (c01 - c00);
            const float fyb = c10 + wx * (c11 - c10);
            const float fy  = fyt + wy * (fyb - fyt);

            // grid_sample border, align_corners: sample at (gx + 4*fx, gy + 4*fy)
            const float gxs = fminf(fmaxf(fmaf(4.0f, fx, (float)gx), 0.0f), (float)(W_ - 1));
            const float gys = fminf(fmaxf(fmaf(4.0f, fy, (float)gy), 0.0f), (float)(H_ - 1));
            const int sx0 = (int)gxs, sy0 = (int)gys;
            const int sx1 = min(sx0 + 1, W_ - 1);
            const int sy1 = min(sy0 + 1, H_ - 1);
            const float swx = gxs - (float)sx0, swy = gys - (float)sy0;
            const uint32_t p00 = (uint32_t)sy0 * W_ + (uint32_t)sx0;
            const uint32_t p01 = (uint32_t)sy0 * W_ + (uint32_t)sx1;
            const uint32_t p10 = (uint32_t)sy1 * W_ + (uint32_t)sx0;
            const uint32_t p11 = (uint32_t)sy1 * W_ + (uint32_t)sx1;

            {
                const float t = i20[p00] + swx * (i20[p01] - i20[p00]);
                const float u = i20[p10] + swx * (i20[p11] - i20[p10]);
                v20 = t + swy * (u - t);
            }
            {
                const float t = i21[p00] + swx * (i21[p01] - i21[p00]);
                const float u = i21[p10] + swx * (i21[p11] - i21[p10]);
                v21 = t + swy * (u - t);
            }
            {
                const float t = i22[p00] + swx * (i22[p01] - i22[p00]);
                const float u = i22[p10] + swx * (i22[p11] - i22[p10]);
                v22 = t + swy * (u - t);
            }
        }
        s1[0][ly][lx] = v10; s1[1][ly][lx] = v11; s1[2][ly][lx] = v12;
        s2[0][ly][lx] = v20; s2[1][ly][lx] = v21; s2[2][ly][lx] = v22;
    }

    // ---- Mask loads (before barrier: overlap with staging latency) ----
    const int lx  = tid & 63;            // column 0..63
    const int lyg = tid >> 6;            // row group 0..3 -> rows lyg*4 .. lyg*4+3
    const int rb  = lyg * 4;
    const float* mb = mask + (size_t)b * plane;
    const uint32_t mb0 = (uint32_t)(ty0 + rb) * W_ + (uint32_t)(tx0 + lx);
    float mreg[4];
    #pragma unroll
    for (int k = 0; k < 4; ++k) mreg[k] = mb[mb0 + (uint32_t)k * W_];

    __syncthreads();

    // ---- Rolling 3x3 SSIM: 1 column x 4 consecutive rows per thread ----
    const float inv9 = 1.0f / 9.0f;
    const float C1 = 0.0001f, C2 = 0.0009f;
    float dist[4] = {0.f, 0.f, 0.f, 0.f};
    float l1s [4] = {0.f, 0.f, 0.f, 0.f};

    #pragma unroll
    for (int c = 0; c < 3; ++c) {
        float hA0,hB0,hAA0,hBB0,hAB0;
        float hA1,hB1,hAA1,hBB1,hAB1;
        float hA2,hB2,hAA2,hBB2,hAB2;
        hrow(&s1[c][rb + 0][lx], &s2[c][rb + 0][lx], hA0,hB0,hAA0,hBB0,hAB0);
        hrow(&s1[c][rb + 1][lx], &s2[c][rb + 1][lx], hA1,hB1,hAA1,hBB1,hAB1);
        #pragma unroll
        for (int k = 0; k < 4; ++k) {
            hrow(&s1[c][rb + k + 2][lx], &s2[c][rb + k + 2][lx], hA2,hB2,hAA2,hBB2,hAB2);
            const float sA  = hA0  + hA1  + hA2;
            const float sB  = hB0  + hB1  + hB2;
            const float sAA = hAA0 + hAA1 + hAA2;
            const float sBB = hBB0 + hBB1 + hBB2;
            const float sAB = hAB0 + hAB1 + hAB2;
            const float mx  = sA * inv9, my = sB * inv9;
            const float vx  = fmaf(-mx, mx, sAA * inv9);
            const float vy  = fmaf(-my, my, sBB * inv9);
            const float vxy = fmaf(-mx, my, sAB * inv9);
            const float numt = (2.f * mx * my + C1) * (2.f * vxy + C2);
            const float dent = fmaf(fmaf(mx, mx, fmaf(my, my, C1)), (vx + vy + C2), 1e-12f);
            const float ssim = numt * __builtin_amdgcn_rcpf(dent);
            dist[k] += fminf(fmaxf((1.0f - ssim) * 0.5f, 0.f), 1.f);
            const float ac = s1[c][rb + k + 1][lx + 1];
            const float bc = s2[c][rb + k + 1][lx + 1];
            l1s[k] += fabsf(ac - bc);
            // roll the window
            hA0 = hA1; hB0 = hB1; hAA0 = hAA1; hBB0 = hBB1; hAB0 = hAB1;
            hA1 = hA2; hB1 = hB2; hAA1 = hAA2; hBB1 = hBB2; hAB1 = hAB2;
        }
    }

    float num_acc = 0.f, den_acc = 0.f;
    #pragma unroll
    for (int k = 0; k < 4; ++k) {
        const float pmv = 0.28333334f * dist[k] + 0.05f * l1s[k];  // 0.85/3, 0.15/3
        const float m   = (mreg[k] > 0.5f) ? 1.f : 0.f;
        num_acc = fmaf(pmv, m, num_acc);
        den_acc += m;
    }

    float num = wave_reduce(num_acc);
    float den = wave_reduce(den_acc);
    __shared__ float rn[4], rd[4];
    const int wid = tid >> 6, lane = tid & 63;
    if (lane == 0) { rn[wid] = num; rd[wid] = den; }
    __syncthreads();
    if (tid == 0) {
        const int lin = (blockIdx.z * gridDim.y + blockIdx.y) * gridDim.x + blockIdx.x;
        float* slot = accum + (size_t)(lin & (NSLOT - 1)) * 4;
        atomicAdd(&slot[0], rn[0] + rn[1] + rn[2] + rn[3]);
        atomicAdd(&slot[1], rd[0] + rd[1] + rd[2] + rd[3]);
    }
}

// Smoothness loss on raw flow: sum |dx| and |dy| separately (different counts).
__global__ __launch_bounds__(256)
void smooth_kernel(const float* __restrict__ flow, float* __restrict__ accum) {
    const int N = B_ * 2 * FH_ * FW_;
    float dxs = 0.f, dys = 0.f;
    for (int i = blockIdx.x * 256 + threadIdx.x; i < N; i += gridDim.x * 256) {
        const float f = flow[i];
        const int x = i & (FW_ - 1);
        const int y = (i >> 8) & (FH_ - 1);
        if (x < FW_ - 1) dxs += fabsf(f - flow[i + 1]);
        if (y < FH_ - 1) dys += fabsf(f - flow[i + FW_]);
    }
    dxs = wave_reduce(dxs);
    dys = wave_reduce(dys);
    __shared__ float rn[4], rd[4];
    const int wid = threadIdx.x >> 6, lane = threadIdx.x & 63;
    if (lane == 0) { rn[wid] = dxs; rd[wid] = dys; }
    __syncthreads();
    if (threadIdx.x == 0) {
        float* slot = accum + (size_t)blockIdx.x * 4;
        atomicAdd(&slot[2], rn[0] + rn[1] + rn[2] + rn[3]);
        atomicAdd(&slot[3], rd[0] + rd[1] + rd[2] + rd[3]);
    }
}

// Reduce the 256 accumulator slots and emit the 3 outputs.
__global__ __launch_bounds__(256)
void finalize_kernel(const float* __restrict__ accum, float* __restrict__ out) {
    const int t = threadIdx.x;
    float num = accum[t * 4 + 0];
    float den = accum[t * 4 + 1];
    float dxs = accum[t * 4 + 2];
    float dys = accum[t * 4 + 3];
    num = wave_reduce(num); den = wave_reduce(den);
    dxs = wave_reduce(dxs); dys = wave_reduce(dys);
    __shared__ float r[4][4];
    const int wid = t >> 6, lane = t & 63;
    if (lane == 0) { r[wid][0] = num; r[wid][1] = den; r[wid][2] = dxs; r[wid][3] = dys; }
    __syncthreads();
    if (t == 0) {
        const float tn = r[0][0] + r[1][0] + r[2][0] + r[3][0];
        const float td = r[0][1] + r[1][1] + r[2][1] + r[3][1];
        const float tx = r[0][2] + r[1][2] + r[2][2] + r[3][2];
        const float ty = r[0][3] + r[1][3] + r[2][3] + r[3][3];
        const float photo   = tn / fmaxf(td, 1.0f);
        const float mean_dx = tx / (float)(B_ * 2 * FH_ * (FW_ - 1));
        const float mean_dy = ty / (float)(B_ * 2 * (FH_ - 1) * FW_);
        const float smooth  = mean_dx + mean_dy;
        out[0] = photo + 0.1f * smooth;   // total
        out[1] = photo;
        out[2] = smooth;
    }
}

extern "C" void kernel_launch(void* const* d_in, const int* in_sizes, int n_in,
                              void* d_out, int out_size, void* d_ws, size_t ws_size,
                              hipStream_t stream) {
    const float* flow = (const float*)d_in[0];
    const float* img1 = (const float*)d_in[1];
    const float* img2 = (const float*)d_in[2];
    const float* mask = (const float*)d_in[3];
    float* out   = (float*)d_out;
    float* accum = (float*)d_ws;   // NSLOT x [num, den, dx_sum, dy_sum]

    hipMemsetAsync(accum, 0, NSLOT * 4 * sizeof(float), stream);
    smooth_kernel<<<NSLOT, 256, 0, stream>>>(flow, accum);
    dim3 grid(W_ / TW, H_ / TH, B_);
    fused_main<<<grid, 256, 0, stream>>>(flow, img1, img2, mask, accum);
    finalize_kernel<<<1, 256, 0, stream>>>(accum, out);
}

// Round 5
// 195.952 us; speedup vs baseline: 2.7908x; 1.0447x over previous
//
#include <hip/hip_runtime.h>
#include <hip/hip_fp16.h>

// Problem constants (fixed by setup_inputs)
#define B_   8
#define H_   512
#define W_   1024
#define FH_  128
#define FW_  256
#define TW   64
#define TH   16
#define HW_  (TW + 2)    // 66
#define HH_  (TH + 2)    // 18
#define NHALO (HH_ * HW_) // 1188
#define FR_  8           // staged flow rows
#define FC_  20          // staged flow cols
#define NSLOT 256

__device__ __forceinline__ float wave_reduce(float v) {
    #pragma unroll
    for (int off = 32; off > 0; off >>= 1) v += __shfl_down(v, off, 64);
    return v;
}

// Horizontal 3-col sums of the 5 SSIM quantities from one packed LDS row.
// .x = img1 value, .y = warped img2 value.
__device__ __forceinline__ void hrow(const __half2* __restrict__ s,
                                     float& hA, float& hB, float& hAA, float& hBB, float& hAB) {
    const float2 p0 = __half22float2(s[0]);
    const float2 p1 = __half22float2(s[1]);
    const float2 p2 = __half22float2(s[2]);
    hA  = p0.x + p1.x + p2.x;
    hB  = p0.y + p1.y + p2.y;
    hAA = fmaf(p0.x, p0.x, fmaf(p1.x, p1.x, p2.x * p2.x));
    hBB = fmaf(p0.y, p0.y, fmaf(p1.y, p1.y, p2.y * p2.y));
    hAB = fmaf(p0.x, p0.y, fmaf(p1.x, p1.y, p2.x * p2.y));
}

// Fused: per 64x16 tile, stage flow footprint in LDS, then (66x18) halo of
// packed (img1, warped img2) half2 in LDS, rolling-window 3x3 SSIM
// (1 column x 4 consecutive rows per thread), masked accumulation.
__global__ __launch_bounds__(256, 5)
void fused_main(const float* __restrict__ flow, const float* __restrict__ img1,
                const float* __restrict__ img2, const float* __restrict__ mask,
                float* __restrict__ accum) {
    // XCD-aware swizzle: 4096 blocks = 8 XCDs x 512; each XCD owns one batch image.
    const int bid = blockIdx.x;
    const int lin = (bid & 7) * 512 + (bid >> 3);
    const int b   = lin >> 9;            // 0..7
    const int rem = lin & 511;
    const int ty0 = (rem >> 4) * TH;     // 32 y-tiles
    const int tx0 = (rem & 15) * TW;     // 16 x-tiles
    const int tid = threadIdx.x;

    __shared__ __half2 sP[3][HH_][HW_];          // packed (img1, warp) tiles
    __shared__ float   sF[2][FR_][FC_];          // flow footprint

    const uint32_t plane = (uint32_t)H_ * W_;
    const float* f0  = flow + (size_t)b * 2 * FH_ * FW_;
    const float* f1  = f0 + FH_ * FW_;
    const float* i10 = img1 + (size_t)b * 3 * plane;
    const float* i11 = i10 + plane;
    const float* i12 = i11 + plane;
    const float* i20 = img2 + (size_t)b * 3 * plane;
    const float* i21 = i20 + plane;
    const float* i22 = i21 + plane;

    // ---- Phase 0: stage flow footprint (clamped) ----
    const int fx0s = (tx0 > 0) ? (int)((float)(tx0 - 1) * (255.0f / 1023.0f)) : 0;
    const int fy0s = (ty0 > 0) ? (int)((float)(ty0 - 1) * (127.0f / 511.0f)) : 0;
    if (tid < 2 * FR_ * FC_ - 256 || tid < 256) {   // always true; plain loop below
    }
    for (int i = tid; i < 2 * FR_ * FC_; i += 256) {
        const int ch = i / (FR_ * FC_);
        const int r  = (i - ch * FR_ * FC_) / FC_;
        const int cc = i - ch * FR_ * FC_ - r * FC_;
        const int sy = min(fy0s + r, FH_ - 1);
        const int sx = min(fx0s + cc, FW_ - 1);
        const float* fp = ch ? f1 : f0;
        sF[ch][r][cc] = fp[(uint32_t)sy * FW_ + (uint32_t)sx];
    }

    // ---- Mask loads (independent of LDS; overlap with staging latency) ----
    const int lx  = tid & 63;            // column 0..63
    const int lyg = tid >> 6;            // row group 0..3
    const int rb  = lyg * 4;
    const float* mb = mask + (size_t)b * plane;
    const uint32_t mb0 = (uint32_t)(ty0 + rb) * W_ + (uint32_t)(tx0 + lx);
    float mreg[4];
    #pragma unroll
    for (int k = 0; k < 4; ++k) mreg[k] = mb[mb0 + (uint32_t)k * W_];

    __syncthreads();

    // ---- Phase 1: stage halo (img1 + warped img2), 5 unrolled slots ----
    #pragma unroll
    for (int s = 0; s < 5; ++s) {
        const int i = tid + s * 256;
        if (i < NHALO) {
            const int ly = i / HW_;
            const int lxh = i - ly * HW_;
            const int gy = ty0 + ly - 1;
            const int gx = tx0 + lxh - 1;
            float v10 = 0.f, v11 = 0.f, v12 = 0.f;
            float v20 = 0.f, v21 = 0.f, v22 = 0.f;
            if (gy >= 0 && gy < H_ && gx >= 0 && gx < W_) {
                const uint32_t p = (uint32_t)gy * W_ + (uint32_t)gx;
                v10 = i10[p]; v11 = i11[p]; v12 = i12[p];

                // flow upsample from LDS footprint (bilinear align_corners)
                const float yc = gy * (127.0f / 511.0f);
                const float xc = gx * (255.0f / 1023.0f);
                const int y0 = (int)yc, x0 = (int)xc;
                const float wy = yc - (float)y0, wx = xc - (float)x0;
                const int yr = y0 - fy0s, xr = x0 - fx0s;
                const float a00 = sF[0][yr][xr],     a01 = sF[0][yr][xr + 1];
                const float a10 = sF[0][yr + 1][xr], a11 = sF[0][yr + 1][xr + 1];
                const float c00 = sF[1][yr][xr],     c01 = sF[1][yr][xr + 1];
                const float c10 = sF[1][yr + 1][xr], c11 = sF[1][yr + 1][xr + 1];
                const float fxt = a00 + wx * (a01 - a00);
                const float fxb = a10 + wx * (a11 - a10);
                const float fx  = fxt + wy * (fxb - fxt);
                const float fyt = c00 + wx * (c01 - c00);
                const float fyb = c10 + wx * (c11 - c10);
                const float fy  = fyt + wy * (fyb - fyt);

                // grid_sample border, align_corners: sample at (gx+4fx, gy+4fy)
                const float gxs = fminf(fmaxf(fmaf(4.0f, fx, (float)gx), 0.0f), (float)(W_ - 1));
                const float gys = fminf(fmaxf(fmaf(4.0f, fy, (float)gy), 0.0f), (float)(H_ - 1));
                const int sx0 = (int)gxs, sy0 = (int)gys;
                const int sx1 = min(sx0 + 1, W_ - 1);
                const int sy1 = min(sy0 + 1, H_ - 1);
                const float swx = gxs - (float)sx0, swy = gys - (float)sy0;
                const uint32_t p00 = (uint32_t)sy0 * W_ + (uint32_t)sx0;
                const uint32_t p01 = (uint32_t)sy0 * W_ + (uint32_t)sx1;
                const uint32_t p10 = (uint32_t)sy1 * W_ + (uint32_t)sx0;
                const uint32_t p11 = (uint32_t)sy1 * W_ + (uint32_t)sx1;
                {
                    const float t = i20[p00] + swx * (i20[p01] - i20[p00]);
                    const float u = i20[p10] + swx * (i20[p11] - i20[p10]);
                    v20 = t + swy * (u - t);
                }
                {
                    const float t = i21[p00] + swx * (i21[p01] - i21[p00]);
                    const float u = i21[p10] + swx * (i21[p11] - i21[p10]);
                    v21 = t + swy * (u - t);
                }
                {
                    const float t = i22[p00] + swx * (i22[p01] - i22[p00]);
                    const float u = i22[p10] + swx * (i22[p11] - i22[p10]);
                    v22 = t + swy * (u - t);
                }
            }
            sP[0][ly][lxh] = __floats2half2_rn(v10, v20);
            sP[1][ly][lxh] = __floats2half2_rn(v11, v21);
            sP[2][ly][lxh] = __floats2half2_rn(v12, v22);
        }
    }

    __syncthreads();

    // ---- Rolling 3x3 SSIM: 1 column x 4 consecutive rows per thread ----
    const float inv9 = 1.0f / 9.0f;
    const float C1 = 0.0001f, C2 = 0.0009f;
    float dist[4] = {0.f, 0.f, 0.f, 0.f};
    float l1s [4] = {0.f, 0.f, 0.f, 0.f};

    #pragma unroll
    for (int c = 0; c < 3; ++c) {
        float hA0,hB0,hAA0,hBB0,hAB0;
        float hA1,hB1,hAA1,hBB1,hAB1;
        float hA2,hB2,hAA2,hBB2,hAB2;
        hrow(&sP[c][rb + 0][lx], hA0,hB0,hAA0,hBB0,hAB0);
        hrow(&sP[c][rb + 1][lx], hA1,hB1,hAA1,hBB1,hAB1);
        #pragma unroll
        for (int k = 0; k < 4; ++k) {
            hrow(&sP[c][rb + k + 2][lx], hA2,hB2,hAA2,hBB2,hAB2);
            const float sA  = hA0  + hA1  + hA2;
            const float sB  = hB0  + hB1  + hB2;
            const float sAA = hAA0 + hAA1 + hAA2;
            const float sBB = hBB0 + hBB1 + hBB2;
            const float sAB = hAB0 + hAB1 + hAB2;
            const float mx  = sA * inv9, my = sB * inv9;
            const float vx  = fmaf(-mx, mx, sAA * inv9);
            const float vy  = fmaf(-my, my, sBB * inv9);
            const float vxy = fmaf(-mx, my, sAB * inv9);
            const float numt = (2.f * mx * my + C1) * (2.f * vxy + C2);
            const float dent = fmaf(fmaf(mx, mx, fmaf(my, my, C1)), (vx + vy + C2), 1e-12f);
            const float ssim = numt * __builtin_amdgcn_rcpf(dent);
            dist[k] += fminf(fmaxf((1.0f - ssim) * 0.5f, 0.f), 1.f);
            const float2 ctr = __half22float2(sP[c][rb + k + 1][lx + 1]);
            l1s[k] += fabsf(ctr.x - ctr.y);
            hA0 = hA1; hB0 = hB1; hAA0 = hAA1; hBB0 = hBB1; hAB0 = hAB1;
            hA1 = hA2; hB1 = hB2; hAA1 = hAA2; hBB1 = hBB2; hAB1 = hAB2;
        }
    }

    float num_acc = 0.f, den_acc = 0.f;
    #pragma unroll
    for (int k = 0; k < 4; ++k) {
        const float pmv = 0.28333334f * dist[k] + 0.05f * l1s[k];  // 0.85/3, 0.15/3
        const float m   = (mreg[k] > 0.5f) ? 1.f : 0.f;
        num_acc = fmaf(pmv, m, num_acc);
        den_acc += m;
    }

    float num = wave_reduce(num_acc);
    float den = wave_reduce(den_acc);
    __shared__ float rn[4], rd[4];
    const int wid = tid >> 6, lane = tid & 63;
    if (lane == 0) { rn[wid] = num; rd[wid] = den; }
    __syncthreads();
    if (tid == 0) {
        float* slot = accum + (size_t)(bid & (NSLOT - 1)) * 4;
        atomicAdd(&slot[0], rn[0] + rn[1] + rn[2] + rn[3]);
        atomicAdd(&slot[1], rd[0] + rd[1] + rd[2] + rd[3]);
    }
}

// Smoothness loss on raw flow: sum |dx| and |dy| separately (different counts).
__global__ __launch_bounds__(256)
void smooth_kernel(const float* __restrict__ flow, float* __restrict__ accum) {
    const int N = B_ * 2 * FH_ * FW_;
    float dxs = 0.f, dys = 0.f;
    for (int i = blockIdx.x * 256 + threadIdx.x; i < N; i += gridDim.x * 256) {
        const float f = flow[i];
        const int x = i & (FW_ - 1);
        const int y = (i >> 8) & (FH_ - 1);
        if (x < FW_ - 1) dxs += fabsf(f - flow[i + 1]);
        if (y < FH_ - 1) dys += fabsf(f - flow[i + FW_]);
    }
    dxs = wave_reduce(dxs);
    dys = wave_reduce(dys);
    __shared__ float rn[4], rd[4];
    const int wid = threadIdx.x >> 6, lane = threadIdx.x & 63;
    if (lane == 0) { rn[wid] = dxs; rd[wid] = dys; }
    __syncthreads();
    if (threadIdx.x == 0) {
        float* slot = accum + (size_t)blockIdx.x * 4;
        atomicAdd(&slot[2], rn[0] + rn[1] + rn[2] + rn[3]);
        atomicAdd(&slot[3], rd[0] + rd[1] + rd[2] + rd[3]);
    }
}

// Reduce the 256 accumulator slots and emit the 3 outputs.
__global__ __launch_bounds__(256)
void finalize_kernel(const float* __restrict__ accum, float* __restrict__ out) {
    const int t = threadIdx.x;
    float num = accum[t * 4 + 0];
    float den = accum[t * 4 + 1];
    float dxs = accum[t * 4 + 2];
    float dys = accum[t * 4 + 3];
    num = wave_reduce(num); den = wave_reduce(den);
    dxs = wave_reduce(dxs); dys = wave_reduce(dys);
    __shared__ float r[4][4];
    const int wid = t >> 6, lane = t & 63;
    if (lane == 0) { r[wid][0] = num; r[wid][1] = den; r[wid][2] = dxs; r[wid][3] = dys; }
    __syncthreads();
    if (t == 0) {
        const float tn = r[0][0] + r[1][0] + r[2][0] + r[3][0];
        const float td = r[0][1] + r[1][1] + r[2][1] + r[3][1];
        const float tx = r[0][2] + r[1][2] + r[2][2] + r[3][2];
        const float ty = r[0][3] + r[1][3] + r[2][3] + r[3][3];
        const float photo   = tn / fmaxf(td, 1.0f);
        const float mean_dx = tx / (float)(B_ * 2 * FH_ * (FW_ - 1));
        const float mean_dy = ty / (float)(B_ * 2 * (FH_ - 1) * FW_);
        const float smooth  = mean_dx + mean_dy;
        out[0] = photo + 0.1f * smooth;   // total
        out[1] = photo;
        out[2] = smooth;
    }
}

extern "C" void kernel_launch(void* const* d_in, const int* in_sizes, int n_in,
                              void* d_out, int out_size, void* d_ws, size_t ws_size,
                              hipStream_t stream) {
    const float* flow = (const float*)d_in[0];
    const float* img1 = (const float*)d_in[1];
    const float* img2 = (const float*)d_in[2];
    const float* mask = (const float*)d_in[3];
    float* out   = (float*)d_out;
    float* accum = (float*)d_ws;   // NSLOT x [num, den, dx_sum, dy_sum]

    hipMemsetAsync(accum, 0, NSLOT * 4 * sizeof(float), stream);
    smooth_kernel<<<NSLOT, 256, 0, stream>>>(flow, accum);
    fused_main<<<(W_ / TW) * (H_ / TH) * B_, 256, 0, stream>>>(flow, img1, img2, mask, accum);
    finalize_kernel<<<1, 256, 0, stream>>>(accum, out);
}